// Round 1
// baseline (2988.859 us; speedup 1.0000x reference)
//
#include <hip/hip_runtime.h>
#include <hip/hip_bf16.h>

#define N_INST 64
#define N_PTS 8192
#define LATENT 64
#define HIDDEN 256

// ---------------------------------------------------------------------------
// Kernel 1: gate GEMV + top-k (by |gate|, stable ties) -> compact (idx, val)
// ---------------------------------------------------------------------------
struct GateParams {
    const float* latents;
    const float* gw[5];
    const float* gb[5];
    int*   idx_out;   // [5][64][256]
    float* val_out;   // [5][64][256]
    int E[5];
    int K[5];
};

__global__ __launch_bounds__(256) void gate_topk(GateParams P) {
    const int n = blockIdx.x, l = blockIdx.y, t = threadIdx.x;
    const int E = P.E[l], K = P.K[l];
    __shared__ float lat[LATENT];
    __shared__ float gv[1024];   // signed gate values
    __shared__ float ga[1024];   // |gate| (destroyed by sort)
    __shared__ int s_cntgt, s_pos;

    if (t < LATENT) lat[t] = P.latents[(n * 5 + l) * LATENT + t];
    if (t == 0) { s_cntgt = 0; s_pos = 0; }
    __syncthreads();

    const float* gwl = P.gw[l];
    const float* gbl = P.gb[l];
    for (int e = t; e < E; e += 256) {
        float acc = gbl[e];
        const float* row = gwl + e * LATENT;
        #pragma unroll 8
        for (int j = 0; j < LATENT; ++j) acc = fmaf(lat[j], row[j], acc);
        gv[e] = acc;
        ga[e] = fabsf(acc);
    }

    // bitonic sort ascending on ga[0..E)
    for (int size = 2; size <= E; size <<= 1) {
        for (int stride = size >> 1; stride > 0; stride >>= 1) {
            __syncthreads();
            for (int i = t; i < E; i += 256) {
                int j = i ^ stride;
                if (j > i) {
                    float a = ga[i], b = ga[j];
                    bool up = ((i & size) == 0);
                    if ((a > b) == up) { ga[i] = b; ga[j] = a; }
                }
            }
        }
    }
    __syncthreads();
    const float thr = ga[E - K];  // K-th largest |gate|

    for (int e = t; e < E; e += 256)
        if (fabsf(gv[e]) > thr) atomicAdd(&s_cntgt, 1);
    __syncthreads();
    const int needed = K - s_cntgt;  // slots for elements == thr (index order)

    for (int e = t; e < E; e += 256) {
        float a = fabsf(gv[e]);
        bool keep = (a > thr);
        if (!keep && a == thr) {
            int r = 0;
            for (int e2 = 0; e2 < e; ++e2)
                if (fabsf(gv[e2]) == thr) ++r;
            keep = (r < needed);
        }
        if (keep) {
            int pos = atomicAdd(&s_pos, 1);
            P.idx_out[(l * 64 + n) * 256 + pos] = e;
            P.val_out[(l * 64 + n) * 256 + pos] = gv[e];
        }
    }
}

// ---------------------------------------------------------------------------
// Kernel 2: combine expert weights -> W_T[n][i][o] (i-major, pitch=opitch)
// and B_comb[n][o]. LDS-staged transpose: coalesced reads AND writes.
// ---------------------------------------------------------------------------
__global__ __launch_bounds__(256) void combine_w(
        const float* __restrict__ w, const float* __restrict__ b,
        const int* __restrict__ idx_l, const float* __restrict__ val_l,
        float* __restrict__ wt, float* __restrict__ bc,
        int K, int d_in, int d_out, int opitch, int OC) {
    const int oc = blockIdx.x, n = blockIdx.y, t = threadIdx.x;
    const int o0 = oc * OC;
    __shared__ int   sidx[256];
    __shared__ float sval[256];
    __shared__ float tile[4096];  // [i][oo] pitch OC

    if (t < K) { sidx[t] = idx_l[n * 256 + t]; sval[t] = val_l[n * 256 + t]; }
    __syncthreads();

    const int elems = d_in * OC;
    for (int x = t; x < elems; x += 256) {
        const int i = x % d_in;
        const int oo = x / d_in;
        const int o = o0 + oo;
        float acc = 0.f;
        // K is always a multiple of 4 (4,4,32,32,256): unroll x4 for load ILP
        for (int e = 0; e < K; e += 4) {
            float l0 = w[((long)(sidx[e+0] * d_out + o)) * d_in + i];
            float l1 = w[((long)(sidx[e+1] * d_out + o)) * d_in + i];
            float l2 = w[((long)(sidx[e+2] * d_out + o)) * d_in + i];
            float l3 = w[((long)(sidx[e+3] * d_out + o)) * d_in + i];
            acc = fmaf(sval[e+0], l0, acc);
            acc = fmaf(sval[e+1], l1, acc);
            acc = fmaf(sval[e+2], l2, acc);
            acc = fmaf(sval[e+3], l3, acc);
        }
        tile[i * OC + oo] = acc;
    }
    __syncthreads();
    for (int x = t; x < elems; x += 256) {
        const int i = x / OC;
        const int oo = x % OC;
        wt[((long)(n * d_in + i)) * opitch + o0 + oo] = tile[i * OC + oo];
    }
    if (oc == 0) {
        for (int o = t; o < d_out; o += 256) {
            float acc = 0.f;
            for (int e = 0; e < K; ++e)
                acc = fmaf(sval[e], b[sidx[e] * d_out + o], acc);
            bc[n * d_out + o] = acc;
        }
    }
}

// ---------------------------------------------------------------------------
// Kernel 3: fused 5-layer MLP. One block = (instance, 64-point tile).
// Activations live in 64KB LDS [k][p] across all layers (no HBM round-trip).
// Hidden GEMMs: 8x8 micro-tile, A from LDS (broadcast), B streamed from L2
// with register double-buffer (prefetch depth 2).
// ---------------------------------------------------------------------------
struct FusedParams {
    const float* coords;
    const float* wt0; const float* bc0;
    const float* wt1; const float* bc1;
    const float* wt2; const float* bc2;
    const float* wt3; const float* bc3;
    const float* wt4; const float* bc4;   // wt4 pitch 4 (o padded 3->4)
    float* out;
};

__global__ __launch_bounds__(256) void fused_mlp(FusedParams P) {
    __shared__ float Xs[256 * 64];   // [k][p], 64 KB exactly
    const int bid = blockIdx.x;
    const int n = bid >> 7;          // 128 point-tiles per instance
    const int p0 = (bid & 127) * 64;
    const int t = threadIdx.x;

    // ---- layer 0: d_in=2 -> 256, sine ----
    {
        const int p = t & 63, och = t >> 6;  // 4 o-chunks of 64
        const float2 c = ((const float2*)P.coords)[n * N_PTS + p0 + p];
        const float* w0 = P.wt0 + n * 2 * 256;   // [i][o] pitch 256
        const float* b0 = P.bc0 + n * 256;
        #pragma unroll 4
        for (int oo = 0; oo < 64; ++oo) {
            const int o = och * 64 + oo;
            float v = fmaf(c.x, w0[o], fmaf(c.y, w0[256 + o], b0[o]));
            Xs[o * 64 + p] = __sinf(30.f * v);
        }
    }
    __syncthreads();

    // ---- layers 1..3: 256->256 GEMM + sine, in-place in LDS ----
    const int tx = t & 31;   // o-group: o = tx*8 .. +8
    const int ty = t >> 5;   // p-group: p = ty*8 .. +8
    const float* WT[3] = { P.wt1 + n * 65536, P.wt2 + n * 65536, P.wt3 + n * 65536 };
    const float* BC[3] = { P.bc1 + n * 256,   P.bc2 + n * 256,   P.bc3 + n * 256 };

    for (int l = 0; l < 3; ++l) {
        const float* wbase = WT[l] + tx * 8;   // row k at wbase + k*256
        float acc[8][8];
        #pragma unroll
        for (int i = 0; i < 8; ++i)
            #pragma unroll
            for (int j = 0; j < 8; ++j) acc[i][j] = 0.f;

        float4 bq[2][2];
        bq[0][0] = *(const float4*)(wbase + 0);
        bq[0][1] = *(const float4*)(wbase + 4);
        bq[1][0] = *(const float4*)(wbase + 256);
        bq[1][1] = *(const float4*)(wbase + 256 + 4);

        #pragma unroll 4
        for (int k = 0; k < 256; ++k) {
            const float4 a0 = *(const float4*)&Xs[k * 64 + ty * 8];
            const float4 a1 = *(const float4*)&Xs[k * 64 + ty * 8 + 4];
            const float4 b0 = bq[k & 1][0];
            const float4 b1 = bq[k & 1][1];
            const int kpf = (k + 2) & 255;   // wraps harmlessly at the tail
            bq[k & 1][0] = *(const float4*)(wbase + kpf * 256);
            bq[k & 1][1] = *(const float4*)(wbase + kpf * 256 + 4);
            const float av[8] = {a0.x,a0.y,a0.z,a0.w,a1.x,a1.y,a1.z,a1.w};
            const float bv[8] = {b0.x,b0.y,b0.z,b0.w,b1.x,b1.y,b1.z,b1.w};
            #pragma unroll
            for (int i = 0; i < 8; ++i)
                #pragma unroll
                for (int j = 0; j < 8; ++j)
                    acc[i][j] = fmaf(av[i], bv[j], acc[i][j]);
        }

        // bias + sine
        const float* bc = BC[l];
        const float4 bb0 = *(const float4*)(bc + tx * 8);
        const float4 bb1 = *(const float4*)(bc + tx * 8 + 4);
        const float bj[8] = {bb0.x,bb0.y,bb0.z,bb0.w,bb1.x,bb1.y,bb1.z,bb1.w};
        #pragma unroll
        for (int i = 0; i < 8; ++i)
            #pragma unroll
            for (int j = 0; j < 8; ++j)
                acc[i][j] = __sinf(30.f * (acc[i][j] + bj[j]));

        __syncthreads();   // all reads of Xs done before overwrite
        #pragma unroll
        for (int j = 0; j < 8; ++j) {
            const int o = tx * 8 + j;
            float4 y0 = make_float4(acc[0][j], acc[1][j], acc[2][j], acc[3][j]);
            float4 y1 = make_float4(acc[4][j], acc[5][j], acc[6][j], acc[7][j]);
            *(float4*)&Xs[o * 64 + ty * 8]     = y0;
            *(float4*)&Xs[o * 64 + ty * 8 + 4] = y1;
        }
        __syncthreads();
    }

    // ---- layer 4: 256 -> 3 ----
    {
        const int p = t >> 2, o = t & 3;   // o==3 lanes are dead
        const float* wt4 = P.wt4 + n * 256 * 4;   // [k][o] pitch 4
        float acc = (o < 3) ? P.bc4[n * 3 + o] : 0.f;
        #pragma unroll 4
        for (int k = 0; k < 256; ++k)
            acc = fmaf(Xs[k * 64 + p], wt4[k * 4 + o], acc);
        if (o < 3) P.out[((long)(n * N_PTS + p0 + p)) * 3 + o] = acc;
    }
}

// ---------------------------------------------------------------------------
extern "C" void kernel_launch(void* const* d_in, const int* in_sizes, int n_in,
                              void* d_out, int out_size, void* d_ws, size_t ws_size,
                              hipStream_t stream) {
    const float* latents = (const float*)d_in[0];
    const float* coords  = (const float*)d_in[1];
    // dict order: gw0,gb0,gw1,gb1,...  then w0,b0,w1,b1,...
    const float* gw[5] = { (const float*)d_in[2], (const float*)d_in[4],
                           (const float*)d_in[6], (const float*)d_in[8],
                           (const float*)d_in[10] };
    const float* gb[5] = { (const float*)d_in[3], (const float*)d_in[5],
                           (const float*)d_in[7], (const float*)d_in[9],
                           (const float*)d_in[11] };
    const float* w[5]  = { (const float*)d_in[12], (const float*)d_in[14],
                           (const float*)d_in[16], (const float*)d_in[18],
                           (const float*)d_in[20] };
    const float* b[5]  = { (const float*)d_in[13], (const float*)d_in[15],
                           (const float*)d_in[17], (const float*)d_in[19],
                           (const float*)d_in[21] };

    char* ws = (char*)d_ws;
    size_t off = 0;
    auto alloc = [&](size_t bytes) { char* p = ws + off; off += (bytes + 255) & ~(size_t)255; return p; };
    int*   idxl = (int*)  alloc(5 * 64 * 256 * 4);
    float* vall = (float*)alloc(5 * 64 * 256 * 4);
    float* wt0  = (float*)alloc((size_t)64 * 2 * 256 * 4);
    float* wt1  = (float*)alloc((size_t)64 * 256 * 256 * 4);
    float* wt2  = (float*)alloc((size_t)64 * 256 * 256 * 4);
    float* wt3  = (float*)alloc((size_t)64 * 256 * 256 * 4);
    float* wt4  = (float*)alloc((size_t)64 * 256 * 4 * 4);
    float* bc0  = (float*)alloc((size_t)64 * 256 * 4);
    float* bc1  = (float*)alloc((size_t)64 * 256 * 4);
    float* bc2  = (float*)alloc((size_t)64 * 256 * 4);
    float* bc3  = (float*)alloc((size_t)64 * 256 * 4);
    float* bc4  = (float*)alloc((size_t)64 * 3 * 4);

    // 1) gate + top-k
    GateParams gp;
    gp.latents = latents;
    for (int l = 0; l < 5; ++l) { gp.gw[l] = gw[l]; gp.gb[l] = gb[l]; }
    gp.idx_out = idxl; gp.val_out = vall;
    gp.E[0]=8; gp.E[1]=16; gp.E[2]=64; gp.E[3]=256; gp.E[4]=1024;
    gp.K[0]=4; gp.K[1]=4;  gp.K[2]=32; gp.K[3]=32;  gp.K[4]=256;
    hipLaunchKernelGGL(gate_topk, dim3(64, 5), dim3(256), 0, stream, gp);

    // 2) combine per layer: (w, b, idx, val, wt, bc, K, d_in, d_out, opitch, OC)
    hipLaunchKernelGGL(combine_w, dim3(1, 64),  dim3(256), 0, stream,
                       w[0], b[0], idxl + 0*64*256, vall + 0*64*256, wt0, bc0,
                       4, 2, 256, 256, 256);
    hipLaunchKernelGGL(combine_w, dim3(16, 64), dim3(256), 0, stream,
                       w[1], b[1], idxl + 1*64*256, vall + 1*64*256, wt1, bc1,
                       4, 256, 256, 256, 16);
    hipLaunchKernelGGL(combine_w, dim3(16, 64), dim3(256), 0, stream,
                       w[2], b[2], idxl + 2*64*256, vall + 2*64*256, wt2, bc2,
                       32, 256, 256, 256, 16);
    hipLaunchKernelGGL(combine_w, dim3(16, 64), dim3(256), 0, stream,
                       w[3], b[3], idxl + 3*64*256, vall + 3*64*256, wt3, bc3,
                       32, 256, 256, 256, 16);
    hipLaunchKernelGGL(combine_w, dim3(1, 64),  dim3(256), 0, stream,
                       w[4], b[4], idxl + 4*64*256, vall + 4*64*256, wt4, bc4,
                       256, 256, 3, 4, 3);

    // 3) fused 5-layer MLP
    FusedParams fp;
    fp.coords = coords;
    fp.wt0 = wt0; fp.bc0 = bc0;
    fp.wt1 = wt1; fp.bc1 = bc1;
    fp.wt2 = wt2; fp.bc2 = bc2;
    fp.wt3 = wt3; fp.bc3 = bc3;
    fp.wt4 = wt4; fp.bc4 = bc4;
    fp.out = (float*)d_out;
    hipLaunchKernelGGL(fused_mlp, dim3(64 * 128), dim3(256), 0, stream, fp);
}

// Round 2
// 1362.956 us; speedup vs baseline: 2.1929x; 2.1929x over previous
//
#include <hip/hip_runtime.h>
#include <hip/hip_bf16.h>

#define N_INST 64
#define N_PTS 8192
#define LATENT 64
#define HIDDEN 256

typedef __attribute__((ext_vector_type(8))) short short8;
typedef __attribute__((ext_vector_type(4))) float f32x4;

#define MFMA16(a, b, c) __builtin_amdgcn_mfma_f32_16x16x32_bf16(a, b, c, 0, 0, 0)

__device__ __forceinline__ unsigned short f2bf_rne(float f) {
    unsigned u = __float_as_uint(f);
    u += 0x7fff + ((u >> 16) & 1);
    return (unsigned short)(u >> 16);
}
__device__ __forceinline__ float bf2f(unsigned short h) {
    return __uint_as_float(((unsigned)h) << 16);
}

// ---------------------------------------------------------------------------
// Kernel 1: gate GEMV + top-k (by |gate|, stable ties) -> compact (idx, val)
// ---------------------------------------------------------------------------
struct GateParams {
    const float* latents;
    const float* gw[5];
    const float* gb[5];
    int*   idx_out;   // [5][64][256]
    float* val_out;   // [5][64][256]
    int E[5];
    int K[5];
};

__global__ __launch_bounds__(256) void gate_topk(GateParams P) {
    const int n = blockIdx.x, l = blockIdx.y, t = threadIdx.x;
    const int E = P.E[l], K = P.K[l];
    __shared__ float lat[LATENT];
    __shared__ float gv[1024];
    __shared__ float ga[1024];
    __shared__ int s_cntgt, s_pos;

    if (t < LATENT) lat[t] = P.latents[(n * 5 + l) * LATENT + t];
    if (t == 0) { s_cntgt = 0; s_pos = 0; }
    __syncthreads();

    const float* gwl = P.gw[l];
    const float* gbl = P.gb[l];
    for (int e = t; e < E; e += 256) {
        float acc = gbl[e];
        const float* row = gwl + e * LATENT;
        #pragma unroll 8
        for (int j = 0; j < LATENT; ++j) acc = fmaf(lat[j], row[j], acc);
        gv[e] = acc;
        ga[e] = fabsf(acc);
    }

    for (int size = 2; size <= E; size <<= 1) {
        for (int stride = size >> 1; stride > 0; stride >>= 1) {
            __syncthreads();
            for (int i = t; i < E; i += 256) {
                int j = i ^ stride;
                if (j > i) {
                    float a = ga[i], b = ga[j];
                    bool up = ((i & size) == 0);
                    if ((a > b) == up) { ga[i] = b; ga[j] = a; }
                }
            }
        }
    }
    __syncthreads();
    const float thr = ga[E - K];

    for (int e = t; e < E; e += 256)
        if (fabsf(gv[e]) > thr) atomicAdd(&s_cntgt, 1);
    __syncthreads();
    const int needed = K - s_cntgt;

    for (int e = t; e < E; e += 256) {
        float a = fabsf(gv[e]);
        bool keep = (a > thr);
        if (!keep && a == thr) {
            int r = 0;
            for (int e2 = 0; e2 < e; ++e2)
                if (fabsf(gv[e2]) == thr) ++r;
            keep = (r < needed);
        }
        if (keep) {
            int pos = atomicAdd(&s_pos, 1);
            P.idx_out[(l * 64 + n) * 256 + pos] = e;
            P.val_out[(l * 64 + n) * 256 + pos] = gv[e];
        }
    }
}

// ---------------------------------------------------------------------------
// Kernel 2a: fp32 combine (layers 0 and 4) -> W_T[n][i][o] (pitch=opitch), B_comb
// ---------------------------------------------------------------------------
__global__ __launch_bounds__(256) void combine_w(
        const float* __restrict__ w, const float* __restrict__ b,
        const int* __restrict__ idx_l, const float* __restrict__ val_l,
        float* __restrict__ wt, float* __restrict__ bc,
        int K, int d_in, int d_out, int opitch, int OC) {
    const int oc = blockIdx.x, n = blockIdx.y, t = threadIdx.x;
    const int o0 = oc * OC;
    __shared__ int   sidx[256];
    __shared__ float sval[256];
    __shared__ float tile[4096];

    if (t < K) { sidx[t] = idx_l[n * 256 + t]; sval[t] = val_l[n * 256 + t]; }
    __syncthreads();

    const int elems = d_in * OC;
    for (int x = t; x < elems; x += 256) {
        const int i = x % d_in;
        const int oo = x / d_in;
        const int o = o0 + oo;
        float acc = 0.f;
        for (int e = 0; e < K; e += 4) {
            float l0 = w[((long)(sidx[e+0] * d_out + o)) * d_in + i];
            float l1 = w[((long)(sidx[e+1] * d_out + o)) * d_in + i];
            float l2 = w[((long)(sidx[e+2] * d_out + o)) * d_in + i];
            float l3 = w[((long)(sidx[e+3] * d_out + o)) * d_in + i];
            acc = fmaf(sval[e+0], l0, acc);
            acc = fmaf(sval[e+1], l1, acc);
            acc = fmaf(sval[e+2], l2, acc);
            acc = fmaf(sval[e+3], l3, acc);
        }
        tile[i * OC + oo] = acc;
    }
    __syncthreads();
    for (int x = t; x < elems; x += 256) {
        const int i = x / OC;
        const int oo = x % OC;
        wt[((long)(n * d_in + i)) * opitch + o0 + oo] = tile[i * OC + oo];
    }
    if (oc == 0) {
        for (int o = t; o < d_out; o += 256) {
            float acc = 0.f;
            for (int e = 0; e < K; ++e)
                acc = fmaf(sval[e], b[sidx[e] * d_out + o], acc);
            bc[n * d_out + o] = acc;
        }
    }
}

// ---------------------------------------------------------------------------
// Kernel 2b: split combine for hidden layers (256x256). Emits 2 or 3 bf16
// planes directly in MFMA-B-fragment order:
//   flat = ((kc*16 + nt)*64 + lane)*8 + j  where k = kc*32 + (lane>>4)*8 + j,
//   o = nt*16 + (lane&15). A wave's short8 load at (kc,nt) is then coalesced.
// ---------------------------------------------------------------------------
__global__ __launch_bounds__(256) void combine_split(
        const float* __restrict__ w, const float* __restrict__ b,
        const int* __restrict__ idx_l, const float* __restrict__ val_l,
        unsigned short* __restrict__ Bh, unsigned short* __restrict__ Bm,
        unsigned short* __restrict__ Bl, float* __restrict__ bc,
        int K, int split3) {
    const int n = blockIdx.y, t = threadIdx.x;
    const int x = blockIdx.x * 256 + t;   // 0..65535
    __shared__ int   sidx[256];
    __shared__ float sval[256];
    if (t < K) { sidx[t] = idx_l[n * 256 + t]; sval[t] = val_l[n * 256 + t]; }
    __syncthreads();

    const int j    = x & 7;
    const int lane = (x >> 3) & 63;
    const int idx  = x >> 9;          // 0..127
    const int nt   = idx & 15;
    const int kc   = idx >> 4;
    const int k = kc * 32 + ((lane >> 4) & 3) * 8 + j;
    const int o = nt * 16 + (lane & 15);

    float acc = 0.f;
    for (int e = 0; e < K; e += 4) {
        float l0 = w[((long)(sidx[e+0] * 256 + o)) * 256 + k];
        float l1 = w[((long)(sidx[e+1] * 256 + o)) * 256 + k];
        float l2 = w[((long)(sidx[e+2] * 256 + o)) * 256 + k];
        float l3 = w[((long)(sidx[e+3] * 256 + o)) * 256 + k];
        acc = fmaf(sval[e+0], l0, acc);
        acc = fmaf(sval[e+1], l1, acc);
        acc = fmaf(sval[e+2], l2, acc);
        acc = fmaf(sval[e+3], l3, acc);
    }

    const size_t base = (size_t)n * 65536 + x;
    unsigned short h = f2bf_rne(acc);
    float r = acc - bf2f(h);
    Bh[base] = h;
    if (split3) {
        unsigned short m = f2bf_rne(r);
        float r2 = r - bf2f(m);
        Bm[base] = m;
        Bl[base] = f2bf_rne(r2);
    } else {
        Bl[base] = f2bf_rne(r);
    }

    if (blockIdx.x == 0) {
        float a2 = 0.f;
        for (int e = 0; e < K; ++e)
            a2 = fmaf(sval[e], b[sidx[e] * 256 + t], a2);
        bc[n * 256 + t] = a2;
    }
}

// ---------------------------------------------------------------------------
// Kernel 3: fused 5-layer MLP with split-bf16 MFMA hidden layers.
// Block = (instance, 64-pt tile). Xs: fp32 [k=256][p=64], XOR bank-swizzled:
// value (row, p) lives at word row*64 + (p ^ ((row&7)<<3)).
// Waves split o: wave w owns o in [w*64, w*64+64) for all 64 points.
// ---------------------------------------------------------------------------
struct FusedParams {
    const float* coords;
    const float* wt0; const float* bc0;
    const unsigned short* Bh1; const unsigned short* Bm1; const unsigned short* Bl1; const float* bc1;
    const unsigned short* Bh2; const unsigned short* Bl2; const float* bc2;
    const unsigned short* Bh3; const unsigned short* Bl3; const float* bc3;
    const float* wt4; const float* bc4;
    float* out;
};

template <bool SPLIT3>
__device__ __forceinline__ void hidden_layer(
        float* Xs, const short8* __restrict__ Bh, const short8* __restrict__ Bm,
        const short8* __restrict__ Bl, const float* __restrict__ bc,
        int w, int lane) {
    const int quad = lane >> 4, col = lane & 15;

    f32x4 acc[4][4];   // [ntl][mt]
    #pragma unroll
    for (int a = 0; a < 4; ++a)
        #pragma unroll
        for (int m = 0; m < 4; ++m) acc[a][m] = (f32x4){0.f, 0.f, 0.f, 0.f};

    for (int kc = 0; kc < 8; ++kc) {
        // ---- A fragments from LDS fp32, split into bf16 planes ----
        short8 Ah[4], Am[4], Al[4];
        const int kb = kc * 32 + quad * 8;
        #pragma unroll
        for (int mt = 0; mt < 4; ++mt) {
            const int p = mt * 16 + col;
            float xv[8];
            #pragma unroll
            for (int j = 0; j < 8; ++j)
                xv[j] = Xs[(kb + j) * 64 + (p ^ (j << 3))];
            #pragma unroll
            for (int j = 0; j < 8; ++j) {
                float x = xv[j];
                unsigned short h = f2bf_rne(x);
                float r = x - bf2f(h);
                Ah[mt][j] = (short)h;
                if (SPLIT3) {
                    unsigned short m = f2bf_rne(r);
                    float r2 = r - bf2f(m);
                    Am[mt][j] = (short)m;
                    Al[mt][j] = (short)f2bf_rne(r2);
                } else {
                    Al[mt][j] = (short)f2bf_rne(r);
                }
            }
        }
        // ---- B fragments (global, L2-resident) + MFMAs ----
        #pragma unroll
        for (int ntl = 0; ntl < 4; ++ntl) {
            const int nt = w * 4 + ntl;
            const int bi = (kc * 16 + nt) * 64 + lane;
            short8 bh = Bh[bi];
            short8 bl = Bl[bi];
            if (SPLIT3) {
                short8 bm = Bm[bi];
                #pragma unroll
                for (int mt = 0; mt < 4; ++mt) {
                    acc[ntl][mt] = MFMA16(Ah[mt], bh, acc[ntl][mt]);
                    acc[ntl][mt] = MFMA16(Ah[mt], bm, acc[ntl][mt]);
                    acc[ntl][mt] = MFMA16(Am[mt], bh, acc[ntl][mt]);
                    acc[ntl][mt] = MFMA16(Ah[mt], bl, acc[ntl][mt]);
                    acc[ntl][mt] = MFMA16(Am[mt], bm, acc[ntl][mt]);
                    acc[ntl][mt] = MFMA16(Al[mt], bh, acc[ntl][mt]);
                }
            } else {
                #pragma unroll
                for (int mt = 0; mt < 4; ++mt) {
                    acc[ntl][mt] = MFMA16(Ah[mt], bh, acc[ntl][mt]);
                    acc[ntl][mt] = MFMA16(Ah[mt], bl, acc[ntl][mt]);
                    acc[ntl][mt] = MFMA16(Al[mt], bh, acc[ntl][mt]);
                }
            }
        }
    }
    __syncthreads();   // all Xs reads done before in-place overwrite

    // ---- epilogue: bias + sin, write back to Xs (swizzled, float4) ----
    #pragma unroll
    for (int ntl = 0; ntl < 4; ++ntl) {
        const int o = w * 64 + ntl * 16 + col;
        const float bo = bc[o];
        #pragma unroll
        for (int mt = 0; mt < 4; ++mt) {
            const int p0 = mt * 16 + quad * 4;
            float4 y;
            y.x = __sinf(30.f * (acc[ntl][mt][0] + bo));
            y.y = __sinf(30.f * (acc[ntl][mt][1] + bo));
            y.z = __sinf(30.f * (acc[ntl][mt][2] + bo));
            y.w = __sinf(30.f * (acc[ntl][mt][3] + bo));
            *(float4*)&Xs[o * 64 + (p0 ^ ((o & 7) << 3))] = y;
        }
    }
    __syncthreads();
}

__global__ __launch_bounds__(256, 2) void fused_mlp(FusedParams P) {
    __shared__ float Xs[256 * 64];
    const int bid = blockIdx.x;
    const int n = bid >> 7;
    const int p0g = (bid & 127) * 64;
    const int t = threadIdx.x;
    const int lane = t & 63;
    const int w = t >> 6;

    // ---- layer 0: 2 -> 256, fp32 vector + sine ----
    {
        const int p = t & 63, och = t >> 6;
        const float2 c = ((const float2*)P.coords)[n * N_PTS + p0g + p];
        const float* w0 = P.wt0 + n * 2 * 256;
        const float* b0 = P.bc0 + n * 256;
        #pragma unroll 4
        for (int oo = 0; oo < 64; ++oo) {
            const int o = och * 64 + oo;
            float v = fmaf(c.x, w0[o], fmaf(c.y, w0[256 + o], b0[o]));
            Xs[o * 64 + (p ^ ((o & 7) << 3))] = __sinf(30.f * v);
        }
    }
    __syncthreads();

    // ---- hidden layers via split-bf16 MFMA ----
    hidden_layer<true>(Xs, (const short8*)P.Bh1 + (size_t)n * 8192,
                           (const short8*)P.Bm1 + (size_t)n * 8192,
                           (const short8*)P.Bl1 + (size_t)n * 8192,
                           P.bc1 + n * 256, w, lane);
    hidden_layer<false>(Xs, (const short8*)P.Bh2 + (size_t)n * 8192,
                            (const short8*)P.Bh2 + (size_t)n * 8192,
                            (const short8*)P.Bl2 + (size_t)n * 8192,
                            P.bc2 + n * 256, w, lane);
    hidden_layer<false>(Xs, (const short8*)P.Bh3 + (size_t)n * 8192,
                            (const short8*)P.Bh3 + (size_t)n * 8192,
                            (const short8*)P.Bl3 + (size_t)n * 8192,
                            P.bc3 + n * 256, w, lane);

    // ---- layer 4: 256 -> 3, fp32 vector ----
    {
        const int p = t >> 2, o = t & 3;
        const float* wt4 = P.wt4 + n * 256 * 4;
        float acc = (o < 3) ? P.bc4[n * 3 + o] : 0.f;
        #pragma unroll 4
        for (int k = 0; k < 256; ++k)
            acc = fmaf(Xs[k * 64 + (p ^ ((k & 7) << 3))], wt4[k * 4 + o], acc);
        if (o < 3) P.out[((long)(n * N_PTS + p0g + p)) * 3 + o] = acc;
    }
}

// ---------------------------------------------------------------------------
extern "C" void kernel_launch(void* const* d_in, const int* in_sizes, int n_in,
                              void* d_out, int out_size, void* d_ws, size_t ws_size,
                              hipStream_t stream) {
    const float* latents = (const float*)d_in[0];
    const float* coords  = (const float*)d_in[1];
    const float* gw[5] = { (const float*)d_in[2], (const float*)d_in[4],
                           (const float*)d_in[6], (const float*)d_in[8],
                           (const float*)d_in[10] };
    const float* gb[5] = { (const float*)d_in[3], (const float*)d_in[5],
                           (const float*)d_in[7], (const float*)d_in[9],
                           (const float*)d_in[11] };
    const float* w[5]  = { (const float*)d_in[12], (const float*)d_in[14],
                           (const float*)d_in[16], (const float*)d_in[18],
                           (const float*)d_in[20] };
    const float* b[5]  = { (const float*)d_in[13], (const float*)d_in[15],
                           (const float*)d_in[17], (const float*)d_in[19],
                           (const float*)d_in[21] };

    char* ws = (char*)d_ws;
    size_t off = 0;
    auto alloc = [&](size_t bytes) { char* p = ws + off; off += (bytes + 255) & ~(size_t)255; return p; };
    int*   idxl = (int*)  alloc(5 * 64 * 256 * 4);
    float* vall = (float*)alloc(5 * 64 * 256 * 4);
    float* wt0  = (float*)alloc((size_t)64 * 2 * 256 * 4);
    float* wt4  = (float*)alloc((size_t)64 * 256 * 4 * 4);
    float* bc0  = (float*)alloc((size_t)64 * 256 * 4);
    float* bc1  = (float*)alloc((size_t)64 * 256 * 4);
    float* bc2  = (float*)alloc((size_t)64 * 256 * 4);
    float* bc3  = (float*)alloc((size_t)64 * 256 * 4);
    float* bc4  = (float*)alloc((size_t)64 * 3 * 4);
    const size_t PLANE = (size_t)64 * 65536 * 2;   // 8 MB per bf16 plane
    unsigned short* Bh1 = (unsigned short*)alloc(PLANE);
    unsigned short* Bm1 = (unsigned short*)alloc(PLANE);
    unsigned short* Bl1 = (unsigned short*)alloc(PLANE);
    unsigned short* Bh2 = (unsigned short*)alloc(PLANE);
    unsigned short* Bl2 = (unsigned short*)alloc(PLANE);
    unsigned short* Bh3 = (unsigned short*)alloc(PLANE);
    unsigned short* Bl3 = (unsigned short*)alloc(PLANE);

    // 1) gate + top-k
    GateParams gp;
    gp.latents = latents;
    for (int l = 0; l < 5; ++l) { gp.gw[l] = gw[l]; gp.gb[l] = gb[l]; }
    gp.idx_out = idxl; gp.val_out = vall;
    gp.E[0]=8; gp.E[1]=16; gp.E[2]=64; gp.E[3]=256; gp.E[4]=1024;
    gp.K[0]=4; gp.K[1]=4;  gp.K[2]=32; gp.K[3]=32;  gp.K[4]=256;
    hipLaunchKernelGGL(gate_topk, dim3(64, 5), dim3(256), 0, stream, gp);

    // 2) combine: layer 0 (fp32), layers 1-3 (split bf16 planes), layer 4 (fp32)
    hipLaunchKernelGGL(combine_w, dim3(1, 64),  dim3(256), 0, stream,
                       w[0], b[0], idxl + 0*64*256, vall + 0*64*256, wt0, bc0,
                       4, 2, 256, 256, 256);
    hipLaunchKernelGGL(combine_split, dim3(256, 64), dim3(256), 0, stream,
                       w[1], b[1], idxl + 1*64*256, vall + 1*64*256,
                       Bh1, Bm1, Bl1, bc1, 4, 1);
    hipLaunchKernelGGL(combine_split, dim3(256, 64), dim3(256), 0, stream,
                       w[2], b[2], idxl + 2*64*256, vall + 2*64*256,
                       Bh2, (unsigned short*)0, Bl2, bc2, 32, 0);
    hipLaunchKernelGGL(combine_split, dim3(256, 64), dim3(256), 0, stream,
                       w[3], b[3], idxl + 3*64*256, vall + 3*64*256,
                       Bh3, (unsigned short*)0, Bl3, bc3, 32, 0);
    hipLaunchKernelGGL(combine_w, dim3(1, 64),  dim3(256), 0, stream,
                       w[4], b[4], idxl + 4*64*256, vall + 4*64*256, wt4, bc4,
                       256, 256, 3, 4, 3);

    // 3) fused 5-layer MLP
    FusedParams fp;
    fp.coords = coords;
    fp.wt0 = wt0; fp.bc0 = bc0;
    fp.Bh1 = Bh1; fp.Bm1 = Bm1; fp.Bl1 = Bl1; fp.bc1 = bc1;
    fp.Bh2 = Bh2; fp.Bl2 = Bl2; fp.bc2 = bc2;
    fp.Bh3 = Bh3; fp.Bl3 = Bl3; fp.bc3 = bc3;
    fp.wt4 = wt4; fp.bc4 = bc4;
    fp.out = (float*)d_out;
    hipLaunchKernelGGL(fused_mlp, dim3(64 * 128), dim3(256), 0, stream, fp);
}

// Round 3
// 906.862 us; speedup vs baseline: 3.2958x; 1.5029x over previous
//
#include <hip/hip_runtime.h>
#include <hip/hip_bf16.h>

#define N_INST 64
#define N_PTS 8192
#define LATENT 64
#define HIDDEN 256

typedef __attribute__((ext_vector_type(8))) short short8;
typedef __attribute__((ext_vector_type(4))) float f32x4;

#define MFMA16(a, b, c) __builtin_amdgcn_mfma_f32_16x16x32_bf16(a, b, c, 0, 0, 0)

__device__ __forceinline__ unsigned short f2bf_rne(float f) {
    unsigned u = __float_as_uint(f);
    u += 0x7fff + ((u >> 16) & 1);
    return (unsigned short)(u >> 16);
}
__device__ __forceinline__ float bf2f(unsigned short h) {
    return __uint_as_float(((unsigned)h) << 16);
}

// k-dimension permutation: activation value for output-index o of the previous
// layer is stored at k-position kappa(o). Baked into: A-plane writes (layer-0 +
// hidden epilogues), B-plane k-order (combine_split / combine_b4).
//   j  = ((o>>3)&1)*4 + ((o>>4)&3)   (3 bits, lets one thread pack 4 ntl vals)
//   qk = (o>>1)&3                     (k-quad within 32-k chunk)
//   kc = (o>>6)*2 + (o&1)             (32-k chunk)
__device__ __forceinline__ int kappa(int o) {
    int j  = (((o >> 3) & 1) << 2) | ((o >> 4) & 3);
    int qk = (o >> 1) & 3;
    int kc = ((o >> 6) << 1) | (o & 1);
    return (kc << 5) | (qk << 3) | j;
}

// ---------------------------------------------------------------------------
// Kernel 1: gate GEMV + top-k (by |gate|, stable ties) -> compact (idx, val)
// ---------------------------------------------------------------------------
struct GateParams {
    const float* latents;
    const float* gw[5];
    const float* gb[5];
    int*   idx_out;   // [5][64][256]
    float* val_out;   // [5][64][256]
    int E[5];
    int K[5];
};

__global__ __launch_bounds__(256) void gate_topk(GateParams P) {
    const int n = blockIdx.x, l = blockIdx.y, t = threadIdx.x;
    const int E = P.E[l], K = P.K[l];
    __shared__ float lat[LATENT];
    __shared__ float gv[1024];
    __shared__ float ga[1024];
    __shared__ int s_cntgt, s_pos;

    if (t < LATENT) lat[t] = P.latents[(n * 5 + l) * LATENT + t];
    if (t == 0) { s_cntgt = 0; s_pos = 0; }
    __syncthreads();

    const float* gwl = P.gw[l];
    const float* gbl = P.gb[l];
    for (int e = t; e < E; e += 256) {
        float acc = gbl[e];
        const float* row = gwl + e * LATENT;
        #pragma unroll 8
        for (int j = 0; j < LATENT; ++j) acc = fmaf(lat[j], row[j], acc);
        gv[e] = acc;
        ga[e] = fabsf(acc);
    }

    for (int size = 2; size <= E; size <<= 1) {
        for (int stride = size >> 1; stride > 0; stride >>= 1) {
            __syncthreads();
            for (int i = t; i < E; i += 256) {
                int j = i ^ stride;
                if (j > i) {
                    float a = ga[i], b = ga[j];
                    bool up = ((i & size) == 0);
                    if ((a > b) == up) { ga[i] = b; ga[j] = a; }
                }
            }
        }
    }
    __syncthreads();
    const float thr = ga[E - K];

    for (int e = t; e < E; e += 256)
        if (fabsf(gv[e]) > thr) atomicAdd(&s_cntgt, 1);
    __syncthreads();
    const int needed = K - s_cntgt;

    for (int e = t; e < E; e += 256) {
        float a = fabsf(gv[e]);
        bool keep = (a > thr);
        if (!keep && a == thr) {
            int r = 0;
            for (int e2 = 0; e2 < e; ++e2)
                if (fabsf(gv[e2]) == thr) ++r;
            keep = (r < needed);
        }
        if (keep) {
            int pos = atomicAdd(&s_pos, 1);
            P.idx_out[(l * 64 + n) * 256 + pos] = e;
            P.val_out[(l * 64 + n) * 256 + pos] = gv[e];
        }
    }
}

// ---------------------------------------------------------------------------
// Kernel 2a: fp32 combine for layer 0 -> W_T[n][i][o] (pitch 256) + bias
// ---------------------------------------------------------------------------
__global__ __launch_bounds__(256) void combine_w(
        const float* __restrict__ w, const float* __restrict__ b,
        const int* __restrict__ idx_l, const float* __restrict__ val_l,
        float* __restrict__ wt, float* __restrict__ bc,
        int K, int d_in, int d_out, int opitch, int OC) {
    const int oc = blockIdx.x, n = blockIdx.y, t = threadIdx.x;
    const int o0 = oc * OC;
    __shared__ int   sidx[256];
    __shared__ float sval[256];
    __shared__ float tile[4096];

    if (t < K) { sidx[t] = idx_l[n * 256 + t]; sval[t] = val_l[n * 256 + t]; }
    __syncthreads();

    const int elems = d_in * OC;
    for (int x = t; x < elems; x += 256) {
        const int i = x % d_in;
        const int oo = x / d_in;
        const int o = o0 + oo;
        float acc = 0.f;
        for (int e = 0; e < K; e += 4) {
            float l0 = w[((long)(sidx[e+0] * d_out + o)) * d_in + i];
            float l1 = w[((long)(sidx[e+1] * d_out + o)) * d_in + i];
            float l2 = w[((long)(sidx[e+2] * d_out + o)) * d_in + i];
            float l3 = w[((long)(sidx[e+3] * d_out + o)) * d_in + i];
            acc = fmaf(sval[e+0], l0, acc);
            acc = fmaf(sval[e+1], l1, acc);
            acc = fmaf(sval[e+2], l2, acc);
            acc = fmaf(sval[e+3], l3, acc);
        }
        tile[i * OC + oo] = acc;
    }
    __syncthreads();
    for (int x = t; x < elems; x += 256) {
        const int i = x / OC;
        const int oo = x % OC;
        wt[((long)(n * d_in + i)) * opitch + o0 + oo] = tile[i * OC + oo];
    }
    if (oc == 0) {
        for (int o = t; o < d_out; o += 256) {
            float acc = 0.f;
            for (int e = 0; e < K; ++e)
                acc = fmaf(sval[e], b[sidx[e] * d_out + o], acc);
            bc[n * d_out + o] = acc;
        }
    }
}

// ---------------------------------------------------------------------------
// Kernel 2b: hidden-layer combine (256x256). Coalesced reads (lanes span k),
// split to 2 bf16 planes in B-fragment order with kappa-permuted k.
// flat = ((kc*16 + nt)*64 + qk*16 + (o&15))*8 + j
// ---------------------------------------------------------------------------
__global__ __launch_bounds__(256) void combine_split(
        const float* __restrict__ w, const float* __restrict__ b,
        const int* __restrict__ idx_l, const float* __restrict__ val_l,
        unsigned short* __restrict__ Bh, unsigned short* __restrict__ Bl,
        float* __restrict__ bc, int K) {
    const int n = blockIdx.y, t = threadIdx.x;
    const int wv = t >> 6, lane = t & 63;
    __shared__ int   sidx[256];
    __shared__ float sval[256];
    if (t < K) { sidx[t] = idx_l[n * 256 + t]; sval[t] = val_l[n * 256 + t]; }
    __syncthreads();

    unsigned short* Bhn = Bh + (size_t)n * 65536;
    unsigned short* Bln = Bl + (size_t)n * 65536;

    #pragma unroll
    for (int oo = 0; oo < 4; ++oo) {
        const int o = blockIdx.x * 16 + wv * 4 + oo;
        const int nt = o >> 4, colo = o & 15;
        #pragma unroll
        for (int kk = 0; kk < 4; ++kk) {
            const int k = kk * 64 + lane;
            float acc = 0.f;
            for (int e = 0; e < K; e += 4) {
                float l0 = w[((long)(sidx[e+0] * 256 + o)) * 256 + k];
                float l1 = w[((long)(sidx[e+1] * 256 + o)) * 256 + k];
                float l2 = w[((long)(sidx[e+2] * 256 + o)) * 256 + k];
                float l3 = w[((long)(sidx[e+3] * 256 + o)) * 256 + k];
                acc = fmaf(sval[e+0], l0, acc);
                acc = fmaf(sval[e+1], l1, acc);
                acc = fmaf(sval[e+2], l2, acc);
                acc = fmaf(sval[e+3], l3, acc);
            }
            const int kap = kappa(k);
            const int kc = kap >> 5, qk = (kap >> 3) & 3, j = kap & 7;
            const int flat = (((kc * 16 + nt) << 6) + (qk << 4) + colo) * 8 + j;
            unsigned short h = f2bf_rne(acc);
            Bhn[flat] = h;
            Bln[flat] = f2bf_rne(acc - bf2f(h));
        }
    }
    if (blockIdx.x == 0) {
        float a2 = 0.f;
        for (int e = 0; e < K; ++e)
            a2 = fmaf(sval[e], b[sidx[e] * 256 + t], a2);
        bc[n * 256 + t] = a2;
    }
}

// ---------------------------------------------------------------------------
// Kernel 2c: layer-4 combine -> B-fragment planes [8kc][64lane][8j] (16 cols,
// only cols 0..2 written; others read poison, harmlessly unused) + bias.
// ---------------------------------------------------------------------------
__global__ __launch_bounds__(256) void combine_b4(
        const float* __restrict__ w4, const float* __restrict__ b4,
        const int* __restrict__ idx_l, const float* __restrict__ val_l,
        unsigned short* __restrict__ Bh, unsigned short* __restrict__ Bl,
        float* __restrict__ bc) {
    const int n = blockIdx.x, t = threadIdx.x;
    __shared__ int   sidx[256];
    __shared__ float sval[256];
    sidx[t] = idx_l[n * 256 + t]; sval[t] = val_l[n * 256 + t];
    __syncthreads();

    float a0 = 0.f, a1 = 0.f, a2 = 0.f;
    for (int e = 0; e < 256; ++e) {
        const float g = sval[e];
        const long base = (long)sidx[e] * 3 * 256 + t;
        a0 = fmaf(g, w4[base + 0 * 256], a0);
        a1 = fmaf(g, w4[base + 1 * 256], a1);
        a2 = fmaf(g, w4[base + 2 * 256], a2);
    }
    const int kap = kappa(t);
    const int kc = kap >> 5, qk = (kap >> 3) & 3, j = kap & 7;
    unsigned short* Bhn = Bh + n * 4096;
    unsigned short* Bln = Bl + n * 4096;
    float av[3] = {a0, a1, a2};
    #pragma unroll
    for (int o = 0; o < 3; ++o) {
        const int flat = ((kc << 6) + (qk << 4) + o) * 8 + j;
        unsigned short h = f2bf_rne(av[o]);
        Bhn[flat] = h;
        Bln[flat] = f2bf_rne(av[o] - bf2f(h));
    }
    if (t < 3) {
        float s = 0.f;
        for (int e = 0; e < 256; ++e)
            s = fmaf(sval[e], b4[sidx[e] * 3 + t], s);
        bc[n * 3 + t] = s;
    }
}

// ---------------------------------------------------------------------------
// Kernel 3: fused 5-layer MLP. Activations live ONLY as split-bf16 MFMA-A
// fragment planes in LDS (Ah=PL[0], Al=PL[1], 32KB each). Granule g holds 8
// k-consecutive (kappa-order) shorts for one (k-chunk, p); swizzle g^=(g>>4)&3.
// ---------------------------------------------------------------------------
struct FusedParams {
    const float* coords;
    const float* wt0; const float* bc0;
    const unsigned short* Bh1; const unsigned short* Bl1; const float* bc1;
    const unsigned short* Bh2; const unsigned short* Bl2; const float* bc2;
    const unsigned short* Bh3; const unsigned short* Bl3; const float* bc3;
    const unsigned short* Bh4; const unsigned short* Bl4; const float* bc4;
    float* out;
};

__device__ __forceinline__ void hidden_layer(
        unsigned short (*PL)[16384],
        const short8* __restrict__ Bh, const short8* __restrict__ Bl,
        const float* __restrict__ bc, int w, int lane) {
    const int quad = lane >> 4, col = lane & 15;

    f32x4 acc[4][4];   // [ntl][mt]
    #pragma unroll
    for (int a = 0; a < 4; ++a)
        #pragma unroll
        for (int m = 0; m < 4; ++m) acc[a][m] = (f32x4){0.f, 0.f, 0.f, 0.f};

    // prefetch B for kc=0
    short8 bhق[4], blق[4];
    #pragma unroll
    for (int ntl = 0; ntl < 4; ++ntl) {
        const int bi = (w * 4 + ntl) * 64 + lane;
        bhق[ntl] = Bh[bi];
        blق[ntl] = Bl[bi];
    }

    for (int kc = 0; kc < 8; ++kc) {
        // A fragments (both planes) from LDS, vector b128
        short8 Ah[4], Al[4];
        #pragma unroll
        for (int mt = 0; mt < 4; ++mt) {
            int g = (((kc * 4 + mt) << 6) + lane);
            g ^= (g >> 4) & 3;
            Ah[mt] = *(const short8*)&PL[0][g * 8];
            Al[mt] = *(const short8*)&PL[1][g * 8];
        }
        short8 bh[4], bl[4];
        #pragma unroll
        for (int ntl = 0; ntl < 4; ++ntl) { bh[ntl] = bhق[ntl]; bl[ntl] = blق[ntl]; }
        if (kc < 7) {
            #pragma unroll
            for (int ntl = 0; ntl < 4; ++ntl) {
                const int bi = ((kc + 1) * 16 + w * 4 + ntl) * 64 + lane;
                bhق[ntl] = Bh[bi];
                blق[ntl] = Bl[bi];
            }
        }
        #pragma unroll
        for (int ntl = 0; ntl < 4; ++ntl) {
            #pragma unroll
            for (int mt = 0; mt < 4; ++mt) {
                acc[ntl][mt] = MFMA16(Ah[mt], bh[ntl], acc[ntl][mt]);
                acc[ntl][mt] = MFMA16(Ah[mt], bl[ntl], acc[ntl][mt]);
                acc[ntl][mt] = MFMA16(Al[mt], bh[ntl], acc[ntl][mt]);
            }
        }
    }
    __syncthreads();   // all A reads done before in-place overwrite

    // epilogue: bias + sin, split once, write next layer's A planes.
    // For fixed (mt,r) the 4 ntl-values share one granule (j = j0+ntl).
    float bo[4];
    #pragma unroll
    for (int ntl = 0; ntl < 4; ++ntl) bo[ntl] = bc[(w << 6) + (ntl << 4) + col];
    const int qk  = (col >> 1) & 3;
    const int kcW = (w << 1) | (col & 1);
    const int j0  = (col >> 3) << 2;
    #pragma unroll
    for (int mt = 0; mt < 4; ++mt) {
        const int gbase = ((kcW * 4 + mt) << 6) + (qk << 4) + (quad << 2);
        #pragma unroll
        for (int r = 0; r < 4; ++r) {
            int g = gbase + r;
            g ^= (g >> 4) & 3;
            unsigned short hv[4], lv[4];
            #pragma unroll
            for (int ntl = 0; ntl < 4; ++ntl) {
                float x = __sinf(30.f * (acc[ntl][mt][r] + bo[ntl]));
                unsigned short h = f2bf_rne(x);
                hv[ntl] = h;
                lv[ntl] = f2bf_rne(x - bf2f(h));
            }
            uint2 hp, lp;
            hp.x = (unsigned)hv[0] | ((unsigned)hv[1] << 16);
            hp.y = (unsigned)hv[2] | ((unsigned)hv[3] << 16);
            lp.x = (unsigned)lv[0] | ((unsigned)lv[1] << 16);
            lp.y = (unsigned)lv[2] | ((unsigned)lv[3] << 16);
            *(uint2*)&PL[0][g * 8 + j0] = hp;
            *(uint2*)&PL[1][g * 8 + j0] = lp;
        }
    }
    __syncthreads();
}

__global__ __launch_bounds__(256, 2) void fused_mlp(FusedParams P) {
    __shared__ __align__(16) unsigned short PL[2][16384];   // Ah, Al: 64 KB
    const int bid = blockIdx.x;
    const int n = bid >> 7;
    const int p0g = (bid & 127) * 64;
    const int t = threadIdx.x;
    const int lane = t & 63;
    const int w = t >> 6;
    const int quad = lane >> 4, col = lane & 15;

    // ---- layer 0: 2 -> 256, fp32 vector + sine, split-write A planes ----
    {
        const int p = lane;                 // wave w covers o-chunk w
        const float2 c = ((const float2*)P.coords)[n * N_PTS + p0g + p];
        const float* w0 = P.wt0 + n * 512;  // [i][o] pitch 256
        const float* b0 = P.bc0 + n * 256;
        const int mtA = p >> 4, pl = p & 15;
        #pragma unroll
        for (int o210 = 0; o210 < 8; ++o210) {
            const int o0 = o210 & 1, o21 = o210 >> 1;
            const int kc = (w << 1) | o0;
            int g = ((kc * 4 + mtA) << 6) + (o21 << 4) + pl;
            g ^= (g >> 4) & 3;
            short8 hv8, lv8;
            #pragma unroll
            for (int jj = 0; jj < 8; ++jj) {
                const int o3 = jj >> 2, ntl = jj & 3;
                const int o = (w << 6) + (ntl << 4) + (o3 << 3) + (o21 << 1) + o0;
                float v = fmaf(c.x, w0[o], fmaf(c.y, w0[256 + o], b0[o]));
                float x = __sinf(30.f * v);
                unsigned short h = f2bf_rne(x);
                hv8[jj] = (short)h;
                lv8[jj] = (short)f2bf_rne(x - bf2f(h));
            }
            *(short8*)&PL[0][g * 8] = hv8;
            *(short8*)&PL[1][g * 8] = lv8;
        }
    }
    __syncthreads();

    // ---- hidden layers 1..3: split-bf16 MFMA ----
    hidden_layer(PL, (const short8*)P.Bh1 + (size_t)n * 8192,
                     (const short8*)P.Bl1 + (size_t)n * 8192,
                     P.bc1 + n * 256, w, lane);
    hidden_layer(PL, (const short8*)P.Bh2 + (size_t)n * 8192,
                     (const short8*)P.Bl2 + (size_t)n * 8192,
                     P.bc2 + n * 256, w, lane);
    hidden_layer(PL, (const short8*)P.Bh3 + (size_t)n * 8192,
                     (const short8*)P.Bl3 + (size_t)n * 8192,
                     P.bc3 + n * 256, w, lane);

    // ---- layer 4: 256 -> 3 via MFMA; wave w handles p-tile mt=w ----
    {
        const short8* B4h = (const short8*)(P.Bh4 + n * 4096);
        const short8* B4l = (const short8*)(P.Bl4 + n * 4096);
        f32x4 acc4 = (f32x4){0.f, 0.f, 0.f, 0.f};
        #pragma unroll
        for (int kc = 0; kc < 8; ++kc) {
            int g = (((kc * 4 + w) << 6) + lane);
            g ^= (g >> 4) & 3;
            short8 ah = *(const short8*)&PL[0][g * 8];
            short8 al = *(const short8*)&PL[1][g * 8];
            short8 bh = B4h[kc * 64 + lane];
            short8 bl = B4l[kc * 64 + lane];
            acc4 = MFMA16(ah, bh, acc4);
            acc4 = MFMA16(ah, bl, acc4);
            acc4 = MFMA16(al, bh, acc4);
        }
        if (col < 3) {
            const float bo = P.bc4[n * 3 + col];
            #pragma unroll
            for (int r = 0; r < 4; ++r) {
                const int p = (w << 4) + (quad << 2) + r;
                P.out[((long)(n * N_PTS + p0g + p)) * 3 + col] = acc4[r] + bo;
            }
        }
    }
}

// ---------------------------------------------------------------------------
extern "C" void kernel_launch(void* const* d_in, const int* in_sizes, int n_in,
                              void* d_out, int out_size, void* d_ws, size_t ws_size,
                              hipStream_t stream) {
    const float* latents = (const float*)d_in[0];
    const float* coords  = (const float*)d_in[1];
    const float* gw[5] = { (const float*)d_in[2], (const float*)d_in[4],
                           (const float*)d_in[6], (const float*)d_in[8],
                           (const float*)d_in[10] };
    const float* gb[5] = { (const float*)d_in[3], (const float*)d_in[5],
                           (const float*)d_in[7], (const float*)d_in[9],
                           (const float*)d_in[11] };
    const float* w[5]  = { (const float*)d_in[12], (const float*)d_in[14],
                           (const float*)d_in[16], (const float*)d_in[18],
                           (const float*)d_in[20] };
    const float* b[5]  = { (const float*)d_in[13], (const float*)d_in[15],
                           (const float*)d_in[17], (const float*)d_in[19],
                           (const float*)d_in[21] };

    char* ws = (char*)d_ws;
    size_t off = 0;
    auto alloc = [&](size_t bytes) { char* p = ws + off; off += (bytes + 255) & ~(size_t)255; return p; };
    int*   idxl = (int*)  alloc(5 * 64 * 256 * 4);
    float* vall = (float*)alloc(5 * 64 * 256 * 4);
    float* wt0  = (float*)alloc((size_t)64 * 2 * 256 * 4);
    float* bc0  = (float*)alloc((size_t)64 * 256 * 4);
    float* bc1  = (float*)alloc((size_t)64 * 256 * 4);
    float* bc2  = (float*)alloc((size_t)64 * 256 * 4);
    float* bc3  = (float*)alloc((size_t)64 * 256 * 4);
    float* bc4  = (float*)alloc((size_t)64 * 3 * 4);
    const size_t PLANE = (size_t)64 * 65536 * 2;   // 8 MB per bf16 plane
    unsigned short* Bh1 = (unsigned short*)alloc(PLANE);
    unsigned short* Bl1 = (unsigned short*)alloc(PLANE);
    unsigned short* Bh2 = (unsigned short*)alloc(PLANE);
    unsigned short* Bl2 = (unsigned short*)alloc(PLANE);
    unsigned short* Bh3 = (unsigned short*)alloc(PLANE);
    unsigned short* Bl3 = (unsigned short*)alloc(PLANE);
    unsigned short* Bh4 = (unsigned short*)alloc((size_t)64 * 4096 * 2);
    unsigned short* Bl4 = (unsigned short*)alloc((size_t)64 * 4096 * 2);

    // 1) gate + top-k
    GateParams gp;
    gp.latents = latents;
    for (int l = 0; l < 5; ++l) { gp.gw[l] = gw[l]; gp.gb[l] = gb[l]; }
    gp.idx_out = idxl; gp.val_out = vall;
    gp.E[0]=8; gp.E[1]=16; gp.E[2]=64; gp.E[3]=256; gp.E[4]=1024;
    gp.K[0]=4; gp.K[1]=4;  gp.K[2]=32; gp.K[3]=32;  gp.K[4]=256;
    hipLaunchKernelGGL(gate_topk, dim3(64, 5), dim3(256), 0, stream, gp);

    // 2) combines
    hipLaunchKernelGGL(combine_w, dim3(1, 64), dim3(256), 0, stream,
                       w[0], b[0], idxl + 0*64*256, vall + 0*64*256, wt0, bc0,
                       4, 2, 256, 256, 256);
    hipLaunchKernelGGL(combine_split, dim3(16, 64), dim3(256), 0, stream,
                       w[1], b[1], idxl + 1*64*256, vall + 1*64*256,
                       Bh1, Bl1, bc1, 4);
    hipLaunchKernelGGL(combine_split, dim3(16, 64), dim3(256), 0, stream,
                       w[2], b[2], idxl + 2*64*256, vall + 2*64*256,
                       Bh2, Bl2, bc2, 32);
    hipLaunchKernelGGL(combine_split, dim3(16, 64), dim3(256), 0, stream,
                       w[3], b[3], idxl + 3*64*256, vall + 3*64*256,
                       Bh3, Bl3, bc3, 32);
    hipLaunchKernelGGL(combine_b4, dim3(64), dim3(256), 0, stream,
                       w[4], b[4], idxl + 4*64*256, vall + 4*64*256,
                       Bh4, Bl4, bc4);

    // 3) fused 5-layer MLP
    FusedParams fp;
    fp.coords = coords;
    fp.wt0 = wt0; fp.bc0 = bc0;
    fp.Bh1 = Bh1; fp.Bl1 = Bl1; fp.bc1 = bc1;
    fp.Bh2 = Bh2; fp.Bl2 = Bl2; fp.bc2 = bc2;
    fp.Bh3 = Bh3; fp.Bl3 = Bl3; fp.bc3 = bc3;
    fp.Bh4 = Bh4; fp.Bl4 = Bl4; fp.bc4 = bc4;
    fp.out = (float*)d_out;
    hipLaunchKernelGGL(fused_mlp, dim3(64 * 128), dim3(256), 0, stream, fp);
}

// Round 4
// 840.293 us; speedup vs baseline: 3.5569x; 1.0792x over previous
//
#include <hip/hip_runtime.h>
#include <hip/hip_bf16.h>

#define N_PTS 8192
#define LATENT 64

typedef __attribute__((ext_vector_type(8))) short short8;
typedef __attribute__((ext_vector_type(4))) float f32x4;

#define MFMA16(a, b, c) __builtin_amdgcn_mfma_f32_16x16x32_bf16(a, b, c, 0, 0, 0)

__device__ __forceinline__ unsigned short f2bf_rne(float f) {
    unsigned u = __float_as_uint(f);
    u += 0x7fff + ((u >> 16) & 1);
    return (unsigned short)(u >> 16);
}
__device__ __forceinline__ float bf2f(unsigned short h) {
    return __uint_as_float(((unsigned)h) << 16);
}
// pack high-16 of two fp32 bit patterns: low half <- lo>>16, high half <- hi>>16
__device__ __forceinline__ unsigned pack_hi16(unsigned lo, unsigned hi) {
    return __builtin_amdgcn_perm(hi, lo, 0x07060302);
}
// after this add, the high 16 bits are the RNE bf16 of the input pattern
__device__ __forceinline__ unsigned rne_hi(unsigned u) {
    return u + 0x7fff + ((u >> 16) & 1);
}

// k-dimension permutation (kappa): activation for output-index o of the
// previous layer is stored at k-position kappa(o). Baked into A-plane writes
// (epilogues) and B-plane k-order (combine kernels).
__device__ __forceinline__ int kappa(int o) {
    int j  = (((o >> 3) & 1) << 2) | ((o >> 4) & 3);
    int qk = (o >> 1) & 3;
    int kc = ((o >> 6) << 1) | (o & 1);
    return (kc << 5) | (qk << 3) | j;
}

// ---------------------------------------------------------------------------
// Kernel 1: gate GEMV + top-k (by |gate|, stable ties) -> compact (idx, val)
// ---------------------------------------------------------------------------
struct GateParams {
    const float* latents;
    const float* gw[5];
    const float* gb[5];
    int*   idx_out;   // [5][64][256]
    float* val_out;   // [5][64][256]
    int E[5];
    int K[5];
};

__global__ __launch_bounds__(256) void gate_topk(GateParams P) {
    const int n = blockIdx.x, l = blockIdx.y, t = threadIdx.x;
    const int E = P.E[l], K = P.K[l];
    __shared__ float lat[LATENT];
    __shared__ float gv[1024];
    __shared__ float ga[1024];
    __shared__ int s_cntgt, s_pos;

    if (t < LATENT) lat[t] = P.latents[(n * 5 + l) * LATENT + t];
    if (t == 0) { s_cntgt = 0; s_pos = 0; }
    __syncthreads();

    const float* gwl = P.gw[l];
    const float* gbl = P.gb[l];
    for (int e = t; e < E; e += 256) {
        float acc = gbl[e];
        const float* row = gwl + e * LATENT;
        #pragma unroll 8
        for (int j = 0; j < LATENT; ++j) acc = fmaf(lat[j], row[j], acc);
        gv[e] = acc;
        ga[e] = fabsf(acc);
    }

    for (int size = 2; size <= E; size <<= 1) {
        for (int stride = size >> 1; stride > 0; stride >>= 1) {
            __syncthreads();
            for (int i = t; i < E; i += 256) {
                int j = i ^ stride;
                if (j > i) {
                    float a = ga[i], b = ga[j];
                    bool up = ((i & size) == 0);
                    if ((a > b) == up) { ga[i] = b; ga[j] = a; }
                }
            }
        }
    }
    __syncthreads();
    const float thr = ga[E - K];

    for (int e = t; e < E; e += 256)
        if (fabsf(gv[e]) > thr) atomicAdd(&s_cntgt, 1);
    __syncthreads();
    const int needed = K - s_cntgt;

    for (int e = t; e < E; e += 256) {
        float a = fabsf(gv[e]);
        bool keep = (a > thr);
        if (!keep && a == thr) {
            int r = 0;
            for (int e2 = 0; e2 < e; ++e2)
                if (fabsf(gv[e2]) == thr) ++r;
            keep = (r < needed);
        }
        if (keep) {
            int pos = atomicAdd(&s_pos, 1);
            P.idx_out[(l * 64 + n) * 256 + pos] = e;
            P.val_out[(l * 64 + n) * 256 + pos] = gv[e];
        }
    }
}

// ---------------------------------------------------------------------------
// Kernel 2: ALL combines in one launch.
//  blocks [0,64)      : layer-0 W fragment bank (W0F)
//  blocks [64,1088)   : layer-1 split combine (K=4)    n-fastest for L2 reuse
//  blocks [1088,2112) : layer-2 split combine (K=32)
//  blocks [2112,3136) : layer-3 split combine (K=32)
//  blocks [3136,3200) : layer-4 B-frag combine (K=256)
// ---------------------------------------------------------------------------
struct CombParams {
    const float *w0, *b0, *w1, *b1, *w2, *b2, *w3, *b3, *w4, *b4;
    const int* idxl; const float* vall;
    unsigned short* W0F;
    unsigned short *Bh1, *Bl1, *Bh2, *Bl2, *Bh3, *Bl3, *Bh4, *Bl4;
    float *bc1, *bc2, *bc3, *bc4;
};

__global__ __launch_bounds__(256) void combine_all(CombParams C) {
    const int b = blockIdx.x;
    const int t = threadIdx.x;
    __shared__ int   sidx[256];
    __shared__ float sval[256];

    if (b < 64) {
        // ---- layer-0 fragment bank: rows [wxh,wyh,bh,wxl,wyl,bl,wxh,wyh] ----
        const int n = b;
        if (t < 4) { sidx[t] = C.idxl[n * 256 + t]; sval[t] = C.vall[n * 256 + t]; }
        __syncthreads();
        const int o = t;
        float wx = 0.f, wy = 0.f, bb = 0.f;
        #pragma unroll
        for (int e = 0; e < 4; ++e) {
            const float g = sval[e];
            const float2 ww = ((const float2*)C.w0)[sidx[e] * 256 + o];
            wx = fmaf(g, ww.x, wx);
            wy = fmaf(g, ww.y, wy);
            bb = fmaf(g, C.b0[sidx[e] * 256 + o], bb);
        }
        unsigned short wxh = f2bf_rne(wx), wyh = f2bf_rne(wy), bh = f2bf_rne(bb);
        unsigned short wxl = f2bf_rne(wx - bf2f(wxh));
        unsigned short wyl = f2bf_rne(wy - bf2f(wyh));
        unsigned short bl  = f2bf_rne(bb - bf2f(bh));
        const int wv = o >> 6, ntl = (o >> 4) & 3, colo = o & 15;
        short8 frag = { (short)wxh, (short)wyh, (short)bh, (short)wxl,
                        (short)wyl, (short)bl,  (short)wxh, (short)wyh };
        short8 zero = { 0, 0, 0, 0, 0, 0, 0, 0 };
        short8* dst = (short8*)C.W0F + n * 1024 + wv * 256 + ntl * 64 + colo;
        dst[0]  = frag;   // quad 0 holds the live k-slots
        dst[16] = zero;   // quads 1..3 zero
        dst[32] = zero;
        dst[48] = zero;
    } else if (b < 3136) {
        // ---- hidden-layer split combine ----
        int K; const float *w, *bias; unsigned short *Bh, *Bl; float *bc;
        int r, l;
        if (b < 1088)      { l = 1; K = 4;  r = b - 64;   w = C.w1; bias = C.b1; Bh = C.Bh1; Bl = C.Bl1; bc = C.bc1; }
        else if (b < 2112) { l = 2; K = 32; r = b - 1088; w = C.w2; bias = C.b2; Bh = C.Bh2; Bl = C.Bl2; bc = C.bc2; }
        else               { l = 3; K = 32; r = b - 2112; w = C.w3; bias = C.b3; Bh = C.Bh3; Bl = C.Bl3; bc = C.bc3; }
        const int n = r & 63, oc = r >> 6;   // n-fastest: concurrent blocks share expert rows
        const int wv = t >> 6, lane = t & 63;
        if (t < K) { sidx[t] = C.idxl[(l * 64 + n) * 256 + t]; sval[t] = C.vall[(l * 64 + n) * 256 + t]; }
        __syncthreads();

        unsigned short* Bhn = Bh + (size_t)n * 65536;
        unsigned short* Bln = Bl + (size_t)n * 65536;
        #pragma unroll
        for (int oo = 0; oo < 4; ++oo) {
            const int o = oc * 16 + wv * 4 + oo;
            const int nt = o >> 4, colo = o & 15;
            #pragma unroll
            for (int kk = 0; kk < 4; ++kk) {
                const int k = kk * 64 + lane;
                float acc = 0.f;
                for (int e = 0; e < K; e += 4) {
                    float l0 = w[((long)(sidx[e+0] * 256 + o)) * 256 + k];
                    float l1 = w[((long)(sidx[e+1] * 256 + o)) * 256 + k];
                    float l2 = w[((long)(sidx[e+2] * 256 + o)) * 256 + k];
                    float l3 = w[((long)(sidx[e+3] * 256 + o)) * 256 + k];
                    acc = fmaf(sval[e+0], l0, acc);
                    acc = fmaf(sval[e+1], l1, acc);
                    acc = fmaf(sval[e+2], l2, acc);
                    acc = fmaf(sval[e+3], l3, acc);
                }
                const int kap = kappa(k);
                const int kc = kap >> 5, qk = (kap >> 3) & 3, j = kap & 7;
                const int flat = (((kc * 16 + nt) << 6) + (qk << 4) + colo) * 8 + j;
                unsigned short h = f2bf_rne(acc);
                Bhn[flat] = h;
                Bln[flat] = f2bf_rne(acc - bf2f(h));
            }
        }
        if (oc == 0) {
            float a2 = 0.f;
            for (int e = 0; e < K; ++e)
                a2 = fmaf(sval[e], bias[sidx[e] * 256 + t], a2);
            bc[n * 256 + t] = a2;
        }
    } else {
        // ---- layer-4 B-frag combine ----
        const int n = b - 3136;
        sidx[t] = C.idxl[(4 * 64 + n) * 256 + t];
        sval[t] = C.vall[(4 * 64 + n) * 256 + t];
        __syncthreads();
        float a0 = 0.f, a1 = 0.f, a2 = 0.f;
        for (int e = 0; e < 256; ++e) {
            const float g = sval[e];
            const long base = (long)sidx[e] * 3 * 256 + t;
            a0 = fmaf(g, C.w4[base + 0],   a0);
            a1 = fmaf(g, C.w4[base + 256], a1);
            a2 = fmaf(g, C.w4[base + 512], a2);
        }
        const int kap = kappa(t);
        const int kc = kap >> 5, qk = (kap >> 3) & 3, j = kap & 7;
        unsigned short* Bhn = C.Bh4 + n * 4096;
        unsigned short* Bln = C.Bl4 + n * 4096;
        float av[3] = { a0, a1, a2 };
        #pragma unroll
        for (int o = 0; o < 3; ++o) {
            const int flat = ((kc << 6) + (qk << 4) + o) * 8 + j;
            unsigned short h = f2bf_rne(av[o]);
            Bhn[flat] = h;
            Bln[flat] = f2bf_rne(av[o] - bf2f(h));
        }
        if (t < 3) {
            float s = 0.f;
            for (int e = 0; e < 256; ++e)
                s = fmaf(sval[e], C.b4[sidx[e] * 3 + t], s);
            C.bc4[n * 3 + t] = s;
        }
    }
}

// ---------------------------------------------------------------------------
// Kernel 3: fused 5-layer MLP. Activations live as split-bf16 MFMA-A fragment
// planes in LDS. All LDS addresses reduce to one per-thread base + constant
// offsets (swizzle bits depend only on lane).
// ---------------------------------------------------------------------------
struct FusedParams {
    const float* coords;
    const unsigned short* W0F;
    const unsigned short *Bh1, *Bl1; const float* bc1;
    const unsigned short *Bh2, *Bl2; const float* bc2;
    const unsigned short *Bh3, *Bl3; const float* bc3;
    const unsigned short *Bh4, *Bl4; const float* bc4;
    float* out;
};

// epilogue: bias+sin, trunc-split once, perm-pack, write next layer's A planes
__device__ __forceinline__ void epilogue_store(
        unsigned short (*PL)[16384], const f32x4 (*acc)[4], const float* bo30,
        int w, int lane) {
    const int quad = lane >> 4, col = lane & 15;
    const int qk  = (col >> 1) & 3;
    const int kcW = (w << 1) | (col & 1);
    const int j0  = (col >> 3) << 2;
    const int gb  = (kcW * 256 + (qk << 4) + (quad << 2)) * 8 + j0;
    unsigned short* wp0 = &PL[0][gb];
    unsigned short* wp1 = &PL[1][gb];
    #pragma unroll
    for (int mt = 0; mt < 4; ++mt) {
        #pragma unroll
        for (int r = 0; r < 4; ++r) {
            unsigned u[4], v[4];
            #pragma unroll
            for (int ntl = 0; ntl < 4; ++ntl) {
                float x = __sinf(fmaf(acc[ntl][mt][r], 30.f, bo30[ntl]));
                unsigned ux = __float_as_uint(x);
                u[ntl] = ux;
                float rres = x - __uint_as_float(ux & 0xffff0000u);
                v[ntl] = rne_hi(__float_as_uint(rres));
            }
            uint2 hp, lp;
            hp.x = pack_hi16(u[0], u[1]); hp.y = pack_hi16(u[2], u[3]);
            lp.x = pack_hi16(v[0], v[1]); lp.y = pack_hi16(v[2], v[3]);
            const int offs = (mt * 64 + (r ^ qk)) * 8;
            *(uint2*)(wp0 + offs) = hp;
            *(uint2*)(wp1 + offs) = lp;
        }
    }
}

__device__ __forceinline__ void hidden_layer(
        unsigned short (*PL)[16384],
        const short8* __restrict__ Bh, const short8* __restrict__ Bl,
        const float* __restrict__ bc, int w, int lane, int lanep) {
    const int col = lane & 15;
    f32x4 acc[4][4];
    #pragma unroll
    for (int a = 0; a < 4; ++a)
        #pragma unroll
        for (int m = 0; m < 4; ++m) acc[a][m] = (f32x4){0.f, 0.f, 0.f, 0.f};

    const short8* a0 = (const short8*)&PL[0][lanep * 8];
    const short8* a1 = (const short8*)&PL[1][lanep * 8];
    const short8* bph = Bh + (w << 8) + lane;
    const short8* bpl = Bl + (w << 8) + lane;

    short8 pbh[2][4], pbl[2][4];
    #pragma unroll
    for (int ntl = 0; ntl < 4; ++ntl) {
        pbh[0][ntl] = bph[ntl << 6];
        pbl[0][ntl] = bpl[ntl << 6];
    }
    #pragma unroll
    for (int kc = 0; kc < 8; ++kc) {
        const int cur = kc & 1;
        if (kc < 7) {
            #pragma unroll
            for (int ntl = 0; ntl < 4; ++ntl) {
                pbh[cur ^ 1][ntl] = bph[(kc + 1) * 1024 + (ntl << 6)];
                pbl[cur ^ 1][ntl] = bpl[(kc + 1) * 1024 + (ntl << 6)];
            }
        }
        short8 Ah[4], Al[4];
        #pragma unroll
        for (int mt = 0; mt < 4; ++mt) {
            Ah[mt] = a0[(kc * 4 + mt) << 6];
            Al[mt] = a1[(kc * 4 + mt) << 6];
        }
        #pragma unroll
        for (int ntl = 0; ntl < 4; ++ntl) {
            #pragma unroll
            for (int mt = 0; mt < 4; ++mt) {
                acc[ntl][mt] = MFMA16(Ah[mt], pbh[cur][ntl], acc[ntl][mt]);
                acc[ntl][mt] = MFMA16(Ah[mt], pbl[cur][ntl], acc[ntl][mt]);
                acc[ntl][mt] = MFMA16(Al[mt], pbh[cur][ntl], acc[ntl][mt]);
            }
        }
    }
    __syncthreads();   // all A reads done before in-place overwrite

    float bo30[4];
    #pragma unroll
    for (int ntl = 0; ntl < 4; ++ntl)
        bo30[ntl] = 30.f * bc[(w << 6) + (ntl << 4) + col];
    epilogue_store(PL, acc, bo30, w, lane);
    __syncthreads();
}

__global__ __launch_bounds__(256, 2) void fused_mlp(FusedParams P) {
    __shared__ __align__(16) unsigned short PL[2][16384];   // Ah, Al planes
    const int bid = blockIdx.x;
    const int n = bid >> 7;
    const int p0g = (bid & 127) * 64;
    const int t = threadIdx.x;
    const int lane = t & 63, w = t >> 6;
    const int quad = lane >> 4, col = lane & 15;
    const int lanep = lane ^ ((lane >> 4) & 3);

    // ---- layer 0 via MFMA: A = [cxh,cyh,1,cxh,cyh,1,cxl,cyl] in quad-0 ----
    {
        short8 A0[4];
        if (quad == 0) {
            #pragma unroll
            for (int mt = 0; mt < 4; ++mt) {
                const float2 c = ((const float2*)P.coords)[n * N_PTS + p0g + mt * 16 + col];
                unsigned ux = __float_as_uint(c.x), uy = __float_as_uint(c.y);
                unsigned xh = ux & 0xffff0000u, yh = uy & 0xffff0000u;
                unsigned short xl = f2bf_rne(c.x - __uint_as_float(xh));
                unsigned short yl = f2bf_rne(c.y - __uint_as_float(yh));
                short8 a = { (short)(xh >> 16), (short)(yh >> 16), (short)0x3f80,
                             (short)(xh >> 16), (short)(yh >> 16), (short)0x3f80,
                             (short)xl, (short)yl };
                A0[mt] = a;
            }
        } else {
            short8 z = { 0, 0, 0, 0, 0, 0, 0, 0 };
            #pragma unroll
            for (int mt = 0; mt < 4; ++mt) A0[mt] = z;
        }
        f32x4 acc[4][4];
        const short8* b0p = (const short8*)P.W0F + n * 1024 + w * 256 + lane;
        #pragma unroll
        for (int ntl = 0; ntl < 4; ++ntl) {
            const short8 b0 = b0p[ntl << 6];
            #pragma unroll
            for (int mt = 0; mt < 4; ++mt) {
                f32x4 z = (f32x4){0.f, 0.f, 0.f, 0.f};
                acc[ntl][mt] = MFMA16(A0[mt], b0, z);
            }
        }
        const float bz[4] = { 0.f, 0.f, 0.f, 0.f };
        epilogue_store(PL, acc, bz, w, lane);
    }
    __syncthreads();

    // ---- hidden layers 1..3 ----
    hidden_layer(PL, (const short8*)P.Bh1 + (size_t)n * 8192,
                     (const short8*)P.Bl1 + (size_t)n * 8192,
                     P.bc1 + n * 256, w, lane, lanep);
    hidden_layer(PL, (const short8*)P.Bh2 + (size_t)n * 8192,
                     (const short8*)P.Bl2 + (size_t)n * 8192,
                     P.bc2 + n * 256, w, lane, lanep);
    hidden_layer(PL, (const short8*)P.Bh3 + (size_t)n * 8192,
                     (const short8*)P.Bl3 + (size_t)n * 8192,
                     P.bc3 + n * 256, w, lane, lanep);

    // ---- layer 4: 256 -> 3 via MFMA; wave w handles p-tile mt=w ----
    {
        const short8* B4h = (const short8*)P.Bh4 + (n << 9);
        const short8* B4l = (const short8*)P.Bl4 + (n << 9);
        const short8* a0 = (const short8*)&PL[0][lanep * 8];
        const short8* a1 = (const short8*)&PL[1][lanep * 8];
        f32x4 acc4 = (f32x4){0.f, 0.f, 0.f, 0.f};
        #pragma unroll
        for (int kc = 0; kc < 8; ++kc) {
            short8 ah = a0[(kc * 4 + w) << 6];
            short8 al = a1[(kc * 4 + w) << 6];
            short8 bh = B4h[kc * 64 + lane];
            short8 bl = B4l[kc * 64 + lane];
            acc4 = MFMA16(ah, bh, acc4);
            acc4 = MFMA16(ah, bl, acc4);
            acc4 = MFMA16(al, bh, acc4);
        }
        if (col < 3) {
            const float bo = P.bc4[n * 3 + col];
            #pragma unroll
            for (int r = 0; r < 4; ++r) {
                const int p = (w << 4) + (quad << 2) + r;
                P.out[((long)(n * N_PTS + p0g + p)) * 3 + col] = acc4[r] + bo;
            }
        }
    }
}

// ---------------------------------------------------------------------------
extern "C" void kernel_launch(void* const* d_in, const int* in_sizes, int n_in,
                              void* d_out, int out_size, void* d_ws, size_t ws_size,
                              hipStream_t stream) {
    const float* latents = (const float*)d_in[0];
    const float* coords  = (const float*)d_in[1];
    const float* gw[5] = { (const float*)d_in[2], (const float*)d_in[4],
                           (const float*)d_in[6], (const float*)d_in[8],
                           (const float*)d_in[10] };
    const float* gb[5] = { (const float*)d_in[3], (const float*)d_in[5],
                           (const float*)d_in[7], (const float*)d_in[9],
                           (const float*)d_in[11] };
    const float* w[5]  = { (const float*)d_in[12], (const float*)d_in[14],
                           (const float*)d_in[16], (const float*)d_in[18],
                           (const float*)d_in[20] };
    const float* b[5]  = { (const float*)d_in[13], (const float*)d_in[15],
                           (const float*)d_in[17], (const float*)d_in[19],
                           (const float*)d_in[21] };

    char* ws = (char*)d_ws;
    size_t off = 0;
    auto alloc = [&](size_t bytes) { char* p = ws + off; off += (bytes + 255) & ~(size_t)255; return p; };
    int*   idxl = (int*)  alloc(5 * 64 * 256 * 4);
    float* vall = (float*)alloc(5 * 64 * 256 * 4);
    float* bc1  = (float*)alloc((size_t)64 * 256 * 4);
    float* bc2  = (float*)alloc((size_t)64 * 256 * 4);
    float* bc3  = (float*)alloc((size_t)64 * 256 * 4);
    float* bc4  = (float*)alloc((size_t)64 * 3 * 4);
    unsigned short* W0F = (unsigned short*)alloc((size_t)64 * 8192 * 2);
    const size_t PLANE = (size_t)64 * 65536 * 2;   // 8 MB per bf16 plane
    unsigned short* Bh1 = (unsigned short*)alloc(PLANE);
    unsigned short* Bl1 = (unsigned short*)alloc(PLANE);
    unsigned short* Bh2 = (unsigned short*)alloc(PLANE);
    unsigned short* Bl2 = (unsigned short*)alloc(PLANE);
    unsigned short* Bh3 = (unsigned short*)alloc(PLANE);
    unsigned short* Bl3 = (unsigned short*)alloc(PLANE);
    unsigned short* Bh4 = (unsigned short*)alloc((size_t)64 * 4096 * 2);
    unsigned short* Bl4 = (unsigned short*)alloc((size_t)64 * 4096 * 2);

    // 1) gate + top-k
    GateParams gp;
    gp.latents = latents;
    for (int l = 0; l < 5; ++l) { gp.gw[l] = gw[l]; gp.gb[l] = gb[l]; }
    gp.idx_out = idxl; gp.val_out = vall;
    gp.E[0]=8; gp.E[1]=16; gp.E[2]=64; gp.E[3]=256; gp.E[4]=1024;
    gp.K[0]=4; gp.K[1]=4;  gp.K[2]=32; gp.K[3]=32;  gp.K[4]=256;
    hipLaunchKernelGGL(gate_topk, dim3(64, 5), dim3(256), 0, stream, gp);

    // 2) all combines in one launch
    CombParams cp;
    cp.w0 = w[0]; cp.b0 = b[0]; cp.w1 = w[1]; cp.b1 = b[1];
    cp.w2 = w[2]; cp.b2 = b[2]; cp.w3 = w[3]; cp.b3 = b[3];
    cp.w4 = w[4]; cp.b4 = b[4];
    cp.idxl = idxl; cp.vall = vall;
    cp.W0F = W0F;
    cp.Bh1 = Bh1; cp.Bl1 = Bl1; cp.Bh2 = Bh2; cp.Bl2 = Bl2;
    cp.Bh3 = Bh3; cp.Bl3 = Bl3; cp.Bh4 = Bh4; cp.Bl4 = Bl4;
    cp.bc1 = bc1; cp.bc2 = bc2; cp.bc3 = bc3; cp.bc4 = bc4;
    hipLaunchKernelGGL(combine_all, dim3(3200), dim3(256), 0, stream, cp);

    // 3) fused 5-layer MLP
    FusedParams fp;
    fp.coords = coords;
    fp.W0F = W0F;
    fp.Bh1 = Bh1; fp.Bl1 = Bl1; fp.bc1 = bc1;
    fp.Bh2 = Bh2; fp.Bl2 = Bl2; fp.bc2 = bc2;
    fp.Bh3 = Bh3; fp.Bl3 = Bl3; fp.bc3 = bc3;
    fp.Bh4 = Bh4; fp.Bl4 = Bl4; fp.bc4 = bc4;
    fp.out = (float*)d_out;
    hipLaunchKernelGGL(fused_mlp, dim3(64 * 128), dim3(256), 0, stream, fp);
}